// Round 4
// baseline (121.947 us; speedup 1.0000x reference)
//
#include <hip/hip_runtime.h>
#include <hip/hip_bf16.h>
#include <stdint.h>

#define ENT 250000
#define RELSZ 64
#define D 128
#define BATCH 32768
#define KNEG 8

// ---------------- workspace layout (byte offsets) ----------------
// t1       :       0 .. 32768    (64x128 f32)  out_rel - (n_inmap.out_rel) n_inmap
// t2       :   32768 .. 65536    (64x128 f32)  in_rel  - (n_outmap.in_rel) n_outmap
// RR       :   65536 .. 81920    (64x64  f32)  in_rel[i] . out_rel[p]
// C        :   81920 .. 100352   (4608 int)    block bucket counts -> exclusive scan
// rank_pos :  100352 .. 165888   (32768 u16)   block-local stable rank
// rank_neg :  165888 .. 690176   (262144 u16)
// counter  :  690176 .. 690180   (1 int)       k_prep arrive ticket (memset to 0)

__device__ __forceinline__ float logsig(float x) {
  return fminf(x, 0.f) - log1pf(expf(-fabsf(x)));
}

// Fused: blocks [0,128) pos-count (+zero out), [128,1152) neg-count, [1152,1184) tables,
// then the last-arriving block scans C in place.
// Count layout: pos -> C[v*128 + blk]; neg -> C[512 + v*1024 + (blk-128)].
__global__ void k_prep(const float* __restrict__ in_rel, const float* __restrict__ out_rel,
                       const float* __restrict__ in_map, const float* __restrict__ out_map,
                       const int* __restrict__ in_lab, const int* __restrict__ pos_lab,
                       const int* __restrict__ neg_lab,
                       float* __restrict__ t1, float* __restrict__ t2, float* __restrict__ RR,
                       int* __restrict__ C, uint16_t* __restrict__ rank_pos,
                       uint16_t* __restrict__ rank_neg, float* __restrict__ out,
                       int* __restrict__ counter) {
  __shared__ float ls[4];
  __shared__ float sri[2][128];
  __shared__ int wc[4][4];
  __shared__ int wsum[4];
  __shared__ int amLast;
  int blk = blockIdx.x, t = threadIdx.x;

  if (blk >= 1152) {
    // ---- tables: 2 rel rows per block ----
    int sub = t >> 7, tt = t & 127;
    int p = (blk - 1152) * 2 + sub;
    float im = in_map[p * D + tt], om = out_map[p * D + tt];
    float ro = out_rel[p * D + tt], ri = in_rel[p * D + tt];
    float v, r, n_im, n_om;
    v = im * im;
#pragma unroll
    for (int off = 32; off > 0; off >>= 1) v += __shfl_xor(v, off, 64);
    if ((t & 63) == 0) ls[t >> 6] = v;
    __syncthreads();
    r = ls[sub * 2] + ls[sub * 2 + 1];
    n_im = im / fmaxf(sqrtf(r), 1e-12f);
    __syncthreads();
    v = om * om;
#pragma unroll
    for (int off = 32; off > 0; off >>= 1) v += __shfl_xor(v, off, 64);
    if ((t & 63) == 0) ls[t >> 6] = v;
    __syncthreads();
    r = ls[sub * 2] + ls[sub * 2 + 1];
    n_om = om / fmaxf(sqrtf(r), 1e-12f);
    __syncthreads();
    v = n_im * ro;
#pragma unroll
    for (int off = 32; off > 0; off >>= 1) v += __shfl_xor(v, off, 64);
    if ((t & 63) == 0) ls[t >> 6] = v;
    __syncthreads();
    float d1 = ls[sub * 2] + ls[sub * 2 + 1];
    __syncthreads();
    v = n_om * ri;
#pragma unroll
    for (int off = 32; off > 0; off >>= 1) v += __shfl_xor(v, off, 64);
    if ((t & 63) == 0) ls[t >> 6] = v;
    __syncthreads();
    float d2 = ls[sub * 2] + ls[sub * 2 + 1];
    t1[p * D + tt] = ro - d1 * n_im;
    t2[p * D + tt] = ri - d2 * n_om;
    sri[sub][tt] = ri;
    __syncthreads();
    int half = t >> 7, lq = t & 127;
    if (lq < RELSZ) {
      int pr = (blk - 1152) * 2 + half;
      const float* rq = out_rel + lq * D;
      const float* s = sri[half];
      float acc = 0.f;
#pragma unroll 8
      for (int d = 0; d < D; d += 4) {
        float4 r4 = *(const float4*)(rq + d);
        acc += s[d] * r4.x + s[d + 1] * r4.y + s[d + 2] * r4.z + s[d + 3] * r4.w;
      }
      RR[pr * RELSZ + lq] = acc;
    }
  } else {
    // ---- counting + stable block-local ranks ----
    int wave = t >> 6, lane = t & 63;
    int key, i;
    bool is_pos = blk < 128;
    if (is_pos) {
      i = blk * 256 + t;
      int il = in_lab[i], pl = pos_lab[i];
      key = ((il >= ENT) ? 2 : 0) | ((pl >= ENT) ? 1 : 0);
    } else {
      i = (blk - 128) * 256 + t;
      int il = in_lab[i >> 3], nl = neg_lab[i];
      key = ((il >= ENT) ? 2 : 0) | ((nl >= ENT) ? 1 : 0);
    }
    unsigned long long m[4];
#pragma unroll
    for (int v = 0; v < 4; v++) m[v] = __ballot(key == v);
    if (lane < 4) wc[wave][lane] = __popcll(m[lane]);
    int wrank = __popcll(m[key] & ((1ull << lane) - 1ull));
    __syncthreads();
    if (t < 4) {
      int s = wc[0][t] + wc[1][t] + wc[2][t] + wc[3][t];
      int idx = is_pos ? (t * 128 + blk) : (512 + t * 1024 + (blk - 128));
      C[idx] = s;
    }
    int wpre = 0;
    for (int w = 0; w < wave; w++) wpre += wc[w][key];
    uint16_t rk = (uint16_t)(wpre + wrank);
    if (is_pos) { rank_pos[i] = rk; out[i] = 0.f; }
    else        { rank_neg[i] = rk; }
  }

  // ---- arrive; last block scans C[0..4607] (256 thr x 18 elems) ----
  __syncthreads();
  __threadfence();
  if (t == 0) amLast = (atomicAdd(counter, 1) == 1184 - 1) ? 1 : 0;
  __syncthreads();
  if (!amLast) return;
  __threadfence();
  {
    int lane = t & 63, w = t >> 6;
    int base = t * 18;
    int v[18];
    int s = 0;
#pragma unroll
    for (int j = 0; j < 18; j++) { v[j] = C[base + j]; s += v[j]; }
    int inc = s;
#pragma unroll
    for (int off = 1; off < 64; off <<= 1) {
      int x = __shfl_up(inc, off, 64);
      if (lane >= off) inc += x;
    }
    if (lane == 63) wsum[w] = inc;
    __syncthreads();
    int wpre = 0;
    for (int i2 = 0; i2 < w; i2++) wpre += wsum[i2];
    int run = wpre + inc - s;
#pragma unroll
    for (int j = 0; j < 18; j++) { C[base + j] = run; run += v[j]; }
  }
}

// Main: 8 lanes per pair, 8 pairs per wave.
// Blocks [0,1024): pos pairs (8 distinct rows/wave).
// Blocks [1024,9216): neg pairs (one row's 8 negatives/wave; L row broadcast).
__global__ void k_main(const float* __restrict__ in_ent, const float* __restrict__ out_ent,
                       const float* __restrict__ t1, const float* __restrict__ t2,
                       const float* __restrict__ RR,
                       const int* __restrict__ in_lab, const int* __restrict__ pos_lab,
                       const int* __restrict__ neg_lab,
                       const int* __restrict__ C, const uint16_t* __restrict__ rank_pos,
                       const uint16_t* __restrict__ rank_neg, float* __restrict__ out) {
  int blk = blockIdx.x, t = threadIdx.x;
  int wave = t >> 6, lane = t & 63;
  int q = lane & 7, g = lane >> 3;

  bool is_pos = blk < 1024;
  int w = is_pos ? (blk * 4 + wave) : ((blk - 1024) * 4 + wave);
  int i = w * 8 + g;  // pair index within its class

  int il, o;
  if (is_pos) { il = in_lab[i]; o = pos_lab[i]; }
  else        { il = in_lab[w]; o = neg_lab[i]; }
  bool ei = il < ENT;
  int iid = ei ? il : il - ENT;
  bool eo = o < ENT;
  int oid = eo ? o : o - ENT;
  int key = (ei ? 0 : 2) | (eo ? 0 : 1);

  // issue small loads early
  int rk = is_pos ? (int)rank_pos[i] : (int)rank_neg[i];
  int cidx = is_pos ? (key * 128 + (i >> 8)) : (512 + key * 1024 + (i >> 8));
  int cbase = C[cidx];

  const float* Lp = (ei ? in_ent + (size_t)iid * D : t2 + (size_t)iid * D) + q * 4;
  const float* Rp = (eo ? out_ent + (size_t)oid * D : t1 + (size_t)oid * D) + q * 4;
  float4 L0 = *(const float4*)(Lp);
  float4 L1 = *(const float4*)(Lp + 32);
  float4 L2 = *(const float4*)(Lp + 64);
  float4 L3 = *(const float4*)(Lp + 96);
  float4 R0 = *(const float4*)(Rp);
  float4 R1 = *(const float4*)(Rp + 32);
  float4 R2 = *(const float4*)(Rp + 64);
  float4 R3 = *(const float4*)(Rp + 96);

  float p = L0.x * R0.x + L0.y * R0.y + L0.z * R0.z + L0.w * R0.w +
            L1.x * R1.x + L1.y * R1.y + L1.z * R1.z + L1.w * R1.w +
            L2.x * R2.x + L2.y * R2.y + L2.z * R2.z + L2.w * R2.w +
            L3.x * R3.x + L3.y * R3.y + L3.z * R3.z + L3.w * R3.w;
#pragma unroll
  for (int off = 4; off > 0; off >>= 1) p += __shfl_xor(p, off, 64);

  if (q == 0) {
    float dot = p;
    if (!ei && !eo) dot = RR[iid * RELSZ + oid];  // rel-rel pair: exact table value
    int dest;
    float val;
    if (is_pos) { dest = cbase + rk;                 val = logsig(dot); }
    else        { dest = (cbase + rk - BATCH) >> 3;  val = logsig(-dot); }
    atomicAdd(out + dest, -val);
  }
}

extern "C" void kernel_launch(void* const* d_in, const int* in_sizes, int n_in,
                              void* d_out, int out_size, void* d_ws, size_t ws_size,
                              hipStream_t stream) {
  const float* in_ent  = (const float*)d_in[0];
  const float* out_ent = (const float*)d_in[1];
  const float* in_rel  = (const float*)d_in[2];
  const float* out_rel = (const float*)d_in[3];
  const float* in_map  = (const float*)d_in[4];
  const float* out_map = (const float*)d_in[5];
  const int* in_lab  = (const int*)d_in[6];
  const int* pos_lab = (const int*)d_in[7];
  const int* neg_lab = (const int*)d_in[8];

  char* ws = (char*)d_ws;
  float*    t1       = (float*)(ws + 0);
  float*    t2       = (float*)(ws + 32768);
  float*    RR       = (float*)(ws + 65536);
  int*      C        = (int*)(ws + 81920);
  uint16_t* rank_pos = (uint16_t*)(ws + 100352);
  uint16_t* rank_neg = (uint16_t*)(ws + 165888);
  int*      counter  = (int*)(ws + 690176);
  float*    out      = (float*)d_out;

  hipMemsetAsync(counter, 0, 4, stream);
  k_prep<<<1184, 256, 0, stream>>>(in_rel, out_rel, in_map, out_map,
                                   in_lab, pos_lab, neg_lab,
                                   t1, t2, RR, C, rank_pos, rank_neg, out, counter);
  k_main<<<9216, 256, 0, stream>>>(in_ent, out_ent, t1, t2, RR,
                                   in_lab, pos_lab, neg_lab,
                                   C, rank_pos, rank_neg, out);
}

// Round 5
// 44.999 us; speedup vs baseline: 2.7100x; 2.7100x over previous
//
#include <hip/hip_runtime.h>
#include <hip/hip_bf16.h>
#include <stdint.h>

#define ENT 250000
#define RELSZ 64
#define D 128
#define BATCH 32768
#define KNEG 8

// ---------------- workspace layout (byte offsets) ----------------
// t1       :       0 .. 32768    (64x128 f32)  out_rel - (n_inmap.out_rel) n_inmap
// t2       :   32768 .. 65536    (64x128 f32)  in_rel  - (n_outmap.in_rel) n_outmap
// RR       :   65536 .. 81920    (64x64  f32)  in_rel[i] . out_rel[p]
// C        :   81920 .. 100352   (4608 int)    block bucket counts -> exclusive scan
// rank_pos :  100352 .. 165888   (32768 u16)   block-local stable rank
// rank_neg :  165888 .. 690176   (262144 u16)

__device__ __forceinline__ float logsig(float x) {
  return fminf(x, 0.f) - log1pf(expf(-fabsf(x)));
}

// Fused: blocks [0,128) pos-count (+zero out), [128,1152) neg-count, [1152,1184) tables.
// Count layout: pos -> C[v*128 + blk]; neg -> C[512 + v*1024 + (blk-128)].
// NOTE: no device-scope fence / last-block pattern here — R4 measured __threadfence()
// across 1184 blocks at ~73us on MI355X (non-coherent per-XCD L2). Kernel boundary
// ordering (separate k_scan launch, ~3us) is the cheap correct alternative.
__global__ void k_prep(const float* __restrict__ in_rel, const float* __restrict__ out_rel,
                       const float* __restrict__ in_map, const float* __restrict__ out_map,
                       const int* __restrict__ in_lab, const int* __restrict__ pos_lab,
                       const int* __restrict__ neg_lab,
                       float* __restrict__ t1, float* __restrict__ t2, float* __restrict__ RR,
                       int* __restrict__ C, uint16_t* __restrict__ rank_pos,
                       uint16_t* __restrict__ rank_neg, float* __restrict__ out) {
  __shared__ float ls[4];
  __shared__ float sri[2][128];
  __shared__ int wc[4][4];
  int blk = blockIdx.x, t = threadIdx.x;

  if (blk >= 1152) {
    // ---- tables: 2 rel rows per block ----
    int sub = t >> 7, tt = t & 127;
    int p = (blk - 1152) * 2 + sub;
    float im = in_map[p * D + tt], om = out_map[p * D + tt];
    float ro = out_rel[p * D + tt], ri = in_rel[p * D + tt];
    float v, r, n_im, n_om;
    v = im * im;
#pragma unroll
    for (int off = 32; off > 0; off >>= 1) v += __shfl_xor(v, off, 64);
    if ((t & 63) == 0) ls[t >> 6] = v;
    __syncthreads();
    r = ls[sub * 2] + ls[sub * 2 + 1];
    n_im = im / fmaxf(sqrtf(r), 1e-12f);
    __syncthreads();
    v = om * om;
#pragma unroll
    for (int off = 32; off > 0; off >>= 1) v += __shfl_xor(v, off, 64);
    if ((t & 63) == 0) ls[t >> 6] = v;
    __syncthreads();
    r = ls[sub * 2] + ls[sub * 2 + 1];
    n_om = om / fmaxf(sqrtf(r), 1e-12f);
    __syncthreads();
    v = n_im * ro;
#pragma unroll
    for (int off = 32; off > 0; off >>= 1) v += __shfl_xor(v, off, 64);
    if ((t & 63) == 0) ls[t >> 6] = v;
    __syncthreads();
    float d1 = ls[sub * 2] + ls[sub * 2 + 1];
    __syncthreads();
    v = n_om * ri;
#pragma unroll
    for (int off = 32; off > 0; off >>= 1) v += __shfl_xor(v, off, 64);
    if ((t & 63) == 0) ls[t >> 6] = v;
    __syncthreads();
    float d2 = ls[sub * 2] + ls[sub * 2 + 1];
    t1[p * D + tt] = ro - d1 * n_im;
    t2[p * D + tt] = ri - d2 * n_om;
    sri[sub][tt] = ri;
    __syncthreads();
    int half = t >> 7, lq = t & 127;
    if (lq < RELSZ) {
      int pr = (blk - 1152) * 2 + half;
      const float* rq = out_rel + lq * D;
      const float* s = sri[half];
      float acc = 0.f;
#pragma unroll 8
      for (int d = 0; d < D; d += 4) {
        float4 r4 = *(const float4*)(rq + d);
        acc += s[d] * r4.x + s[d + 1] * r4.y + s[d + 2] * r4.z + s[d + 3] * r4.w;
      }
      RR[pr * RELSZ + lq] = acc;
    }
    return;
  }

  // ---- counting + stable block-local ranks ----
  int wave = t >> 6, lane = t & 63;
  int key, i;
  bool is_pos = blk < 128;
  if (is_pos) {
    i = blk * 256 + t;
    int il = in_lab[i], pl = pos_lab[i];
    key = ((il >= ENT) ? 2 : 0) | ((pl >= ENT) ? 1 : 0);
  } else {
    i = (blk - 128) * 256 + t;
    int il = in_lab[i >> 3], nl = neg_lab[i];
    key = ((il >= ENT) ? 2 : 0) | ((nl >= ENT) ? 1 : 0);
  }
  unsigned long long m[4];
#pragma unroll
  for (int v = 0; v < 4; v++) m[v] = __ballot(key == v);
  if (lane < 4) wc[wave][lane] = __popcll(m[lane]);
  int wrank = __popcll(m[key] & ((1ull << lane) - 1ull));
  __syncthreads();
  if (t < 4) {
    int s = wc[0][t] + wc[1][t] + wc[2][t] + wc[3][t];
    int idx = is_pos ? (t * 128 + blk) : (512 + t * 1024 + (blk - 128));
    C[idx] = s;
  }
  int wpre = 0;
  for (int w = 0; w < wave; w++) wpre += wc[w][key];
  uint16_t rk = (uint16_t)(wpre + wrank);
  if (is_pos) { rank_pos[i] = rk; out[i] = 0.f; }
  else        { rank_neg[i] = rk; }
}

// In-place exclusive scan of C[0..4607]. 1 block x 256 threads, 18 elems each.
__global__ void k_scan(int* __restrict__ C) {
  int t = threadIdx.x, lane = t & 63, w = t >> 6;
  int base = t * 18;
  int v[18];
  int s = 0;
#pragma unroll
  for (int j = 0; j < 18; j++) { v[j] = C[base + j]; s += v[j]; }
  int inc = s;
#pragma unroll
  for (int off = 1; off < 64; off <<= 1) {
    int x = __shfl_up(inc, off, 64);
    if (lane >= off) inc += x;
  }
  __shared__ int wsum[4];
  if (lane == 63) wsum[w] = inc;
  __syncthreads();
  int wpre = 0;
  for (int i = 0; i < w; i++) wpre += wsum[i];
  int run = wpre + inc - s;  // exclusive prefix of this thread's chunk
#pragma unroll
  for (int j = 0; j < 18; j++) { C[base + j] = run; run += v[j]; }
}

// Main: 8 lanes per pair, 8 pairs per wave.
// Blocks [0,1024): pos pairs (8 distinct rows/wave).
// Blocks [1024,9216): neg pairs (one row's 8 negatives/wave; L row broadcast).
__global__ void k_main(const float* __restrict__ in_ent, const float* __restrict__ out_ent,
                       const float* __restrict__ t1, const float* __restrict__ t2,
                       const float* __restrict__ RR,
                       const int* __restrict__ in_lab, const int* __restrict__ pos_lab,
                       const int* __restrict__ neg_lab,
                       const int* __restrict__ C, const uint16_t* __restrict__ rank_pos,
                       const uint16_t* __restrict__ rank_neg, float* __restrict__ out) {
  int blk = blockIdx.x, t = threadIdx.x;
  int wave = t >> 6, lane = t & 63;
  int q = lane & 7, g = lane >> 3;

  bool is_pos = blk < 1024;
  int w = is_pos ? (blk * 4 + wave) : ((blk - 1024) * 4 + wave);
  int i = w * 8 + g;  // pair index within its class

  int il, o;
  if (is_pos) { il = in_lab[i]; o = pos_lab[i]; }
  else        { il = in_lab[w]; o = neg_lab[i]; }
  bool ei = il < ENT;
  int iid = ei ? il : il - ENT;
  bool eo = o < ENT;
  int oid = eo ? o : o - ENT;
  int key = (ei ? 0 : 2) | (eo ? 0 : 1);

  // issue small loads early
  int rk = is_pos ? (int)rank_pos[i] : (int)rank_neg[i];
  int cidx = is_pos ? (key * 128 + (i >> 8)) : (512 + key * 1024 + (i >> 8));
  int cbase = C[cidx];

  const float* Lp = (ei ? in_ent + (size_t)iid * D : t2 + (size_t)iid * D) + q * 4;
  const float* Rp = (eo ? out_ent + (size_t)oid * D : t1 + (size_t)oid * D) + q * 4;
  float4 L0 = *(const float4*)(Lp);
  float4 L1 = *(const float4*)(Lp + 32);
  float4 L2 = *(const float4*)(Lp + 64);
  float4 L3 = *(const float4*)(Lp + 96);
  float4 R0 = *(const float4*)(Rp);
  float4 R1 = *(const float4*)(Rp + 32);
  float4 R2 = *(const float4*)(Rp + 64);
  float4 R3 = *(const float4*)(Rp + 96);

  float p = L0.x * R0.x + L0.y * R0.y + L0.z * R0.z + L0.w * R0.w +
            L1.x * R1.x + L1.y * R1.y + L1.z * R1.z + L1.w * R1.w +
            L2.x * R2.x + L2.y * R2.y + L2.z * R2.z + L2.w * R2.w +
            L3.x * R3.x + L3.y * R3.y + L3.z * R3.z + L3.w * R3.w;
#pragma unroll
  for (int off = 4; off > 0; off >>= 1) p += __shfl_xor(p, off, 64);

  if (q == 0) {
    float dot = p;
    if (!ei && !eo) dot = RR[iid * RELSZ + oid];  // rel-rel pair: exact table value
    int dest;
    float val;
    if (is_pos) { dest = cbase + rk;                 val = logsig(dot); }
    else        { dest = (cbase + rk - BATCH) >> 3;  val = logsig(-dot); }
    atomicAdd(out + dest, -val);
  }
}

extern "C" void kernel_launch(void* const* d_in, const int* in_sizes, int n_in,
                              void* d_out, int out_size, void* d_ws, size_t ws_size,
                              hipStream_t stream) {
  const float* in_ent  = (const float*)d_in[0];
  const float* out_ent = (const float*)d_in[1];
  const float* in_rel  = (const float*)d_in[2];
  const float* out_rel = (const float*)d_in[3];
  const float* in_map  = (const float*)d_in[4];
  const float* out_map = (const float*)d_in[5];
  const int* in_lab  = (const int*)d_in[6];
  const int* pos_lab = (const int*)d_in[7];
  const int* neg_lab = (const int*)d_in[8];

  char* ws = (char*)d_ws;
  float*    t1       = (float*)(ws + 0);
  float*    t2       = (float*)(ws + 32768);
  float*    RR       = (float*)(ws + 65536);
  int*      C        = (int*)(ws + 81920);
  uint16_t* rank_pos = (uint16_t*)(ws + 100352);
  uint16_t* rank_neg = (uint16_t*)(ws + 165888);
  float*    out      = (float*)d_out;

  k_prep<<<1184, 256, 0, stream>>>(in_rel, out_rel, in_map, out_map,
                                   in_lab, pos_lab, neg_lab,
                                   t1, t2, RR, C, rank_pos, rank_neg, out);
  k_scan<<<1, 256, 0, stream>>>(C);
  k_main<<<9216, 256, 0, stream>>>(in_ent, out_ent, t1, t2, RR,
                                   in_lab, pos_lab, neg_lab,
                                   C, rank_pos, rank_neg, out);
}

// Round 6
// 43.588 us; speedup vs baseline: 2.7977x; 1.0324x over previous
//
#include <hip/hip_runtime.h>
#include <hip/hip_bf16.h>
#include <stdint.h>

#define ENT 250000
#define RELSZ 64
#define D 128
#define BATCH 32768
#define KNEG 8

// ---------------- workspace layout (byte offsets) ----------------
// t1       :       0 .. 32768    (64x128 f32)  out_rel - (n_inmap.out_rel) n_inmap
// t2       :   32768 .. 65536    (64x128 f32)  in_rel  - (n_outmap.in_rel) n_outmap
// RR       :   65536 .. 81920    (64x64  f32)  in_rel[i] . out_rel[p]
// C        :   81920 .. 100352   (4608 int)    block bucket counts -> exclusive scan
// rank_pos :  100352 .. 165888   (32768 u16)   block-local stable rank
// rank_neg :  165888 .. 690176   (262144 u16)

__device__ __forceinline__ float logsig(float x) {
  return fminf(x, 0.f) - log1pf(expf(-fabsf(x)));
}

// Fused: blocks [0,128) pos-count (+zero out), [128,1152) neg-count, [1152,1184) tables.
// NOTE: no device-scope fence / last-block pattern — R4 measured __threadfence()
// across 1184 blocks at ~73us on MI355X (non-coherent per-XCD L2). Kernel-boundary
// ordering (separate k_scan launch, ~3us) is the cheap correct alternative.
__global__ void k_prep(const float* __restrict__ in_rel, const float* __restrict__ out_rel,
                       const float* __restrict__ in_map, const float* __restrict__ out_map,
                       const int* __restrict__ in_lab, const int* __restrict__ pos_lab,
                       const int* __restrict__ neg_lab,
                       float* __restrict__ t1, float* __restrict__ t2, float* __restrict__ RR,
                       int* __restrict__ C, uint16_t* __restrict__ rank_pos,
                       uint16_t* __restrict__ rank_neg, float* __restrict__ out) {
  __shared__ float ls[4];
  __shared__ float sri[2][128];
  __shared__ int wc[4][4];
  int blk = blockIdx.x, t = threadIdx.x;

  if (blk >= 1152) {
    // ---- tables: 2 rel rows per block ----
    int sub = t >> 7, tt = t & 127;
    int p = (blk - 1152) * 2 + sub;
    float im = in_map[p * D + tt], om = out_map[p * D + tt];
    float ro = out_rel[p * D + tt], ri = in_rel[p * D + tt];
    float v, r, n_im, n_om;
    v = im * im;
#pragma unroll
    for (int off = 32; off > 0; off >>= 1) v += __shfl_xor(v, off, 64);
    if ((t & 63) == 0) ls[t >> 6] = v;
    __syncthreads();
    r = ls[sub * 2] + ls[sub * 2 + 1];
    n_im = im / fmaxf(sqrtf(r), 1e-12f);
    __syncthreads();
    v = om * om;
#pragma unroll
    for (int off = 32; off > 0; off >>= 1) v += __shfl_xor(v, off, 64);
    if ((t & 63) == 0) ls[t >> 6] = v;
    __syncthreads();
    r = ls[sub * 2] + ls[sub * 2 + 1];
    n_om = om / fmaxf(sqrtf(r), 1e-12f);
    __syncthreads();
    v = n_im * ro;
#pragma unroll
    for (int off = 32; off > 0; off >>= 1) v += __shfl_xor(v, off, 64);
    if ((t & 63) == 0) ls[t >> 6] = v;
    __syncthreads();
    float d1 = ls[sub * 2] + ls[sub * 2 + 1];
    __syncthreads();
    v = n_om * ri;
#pragma unroll
    for (int off = 32; off > 0; off >>= 1) v += __shfl_xor(v, off, 64);
    if ((t & 63) == 0) ls[t >> 6] = v;
    __syncthreads();
    float d2 = ls[sub * 2] + ls[sub * 2 + 1];
    t1[p * D + tt] = ro - d1 * n_im;
    t2[p * D + tt] = ri - d2 * n_om;
    sri[sub][tt] = ri;
    __syncthreads();
    int half = t >> 7, lq = t & 127;
    if (lq < RELSZ) {
      int pr = (blk - 1152) * 2 + half;
      const float* rq = out_rel + lq * D;
      const float* s = sri[half];
      float acc = 0.f;
#pragma unroll 8
      for (int d = 0; d < D; d += 4) {
        float4 r4 = *(const float4*)(rq + d);
        acc += s[d] * r4.x + s[d + 1] * r4.y + s[d + 2] * r4.z + s[d + 3] * r4.w;
      }
      RR[pr * RELSZ + lq] = acc;
    }
    return;
  }

  // ---- counting + stable block-local ranks ----
  int wave = t >> 6, lane = t & 63;
  int key, i;
  bool is_pos = blk < 128;
  if (is_pos) {
    i = blk * 256 + t;
    int il = in_lab[i], pl = pos_lab[i];
    key = ((il >= ENT) ? 2 : 0) | ((pl >= ENT) ? 1 : 0);
  } else {
    i = (blk - 128) * 256 + t;
    int il = in_lab[i >> 3], nl = neg_lab[i];
    key = ((il >= ENT) ? 2 : 0) | ((nl >= ENT) ? 1 : 0);
  }
  unsigned long long m[4];
#pragma unroll
  for (int v = 0; v < 4; v++) m[v] = __ballot(key == v);
  if (lane < 4) wc[wave][lane] = __popcll(m[lane]);
  int wrank = __popcll(m[key] & ((1ull << lane) - 1ull));
  __syncthreads();
  if (t < 4) {
    int s = wc[0][t] + wc[1][t] + wc[2][t] + wc[3][t];
    int idx = is_pos ? (t * 128 + blk) : (512 + t * 1024 + (blk - 128));
    C[idx] = s;
  }
  int wpre = 0;
  for (int w = 0; w < wave; w++) wpre += wc[w][key];
  uint16_t rk = (uint16_t)(wpre + wrank);
  if (is_pos) { rank_pos[i] = rk; out[i] = 0.f; }
  else        { rank_neg[i] = rk; }
}

// In-place exclusive scan of C[0..4607]. 1 block x 256 threads, 18 elems each.
__global__ void k_scan(int* __restrict__ C) {
  int t = threadIdx.x, lane = t & 63, w = t >> 6;
  int base = t * 18;
  int v[18];
  int s = 0;
#pragma unroll
  for (int j = 0; j < 18; j++) { v[j] = C[base + j]; s += v[j]; }
  int inc = s;
#pragma unroll
  for (int off = 1; off < 64; off <<= 1) {
    int x = __shfl_up(inc, off, 64);
    if (lane >= off) inc += x;
  }
  __shared__ int wsum[4];
  if (lane == 63) wsum[w] = inc;
  __syncthreads();
  int wpre = 0;
  for (int i = 0; i < w; i++) wpre += wsum[i];
  int run = wpre + inc - s;  // exclusive prefix of this thread's chunk
#pragma unroll
  for (int j = 0; j < 18; j++) { C[base + j] = run; run += v[j]; }
}

// Main: 4 lanes per pair, 16 pairs per wave.
// Blocks [0,512): pos pairs. Blocks [512,4608): neg pairs (2 rows x 8 negs per wave).
// Neg waves combine the up-to-8 same-dest values per row into one atomic (shfl tree
// with dest-equality check; fallback to per-pair atomics on mixed dests).
__global__ void __launch_bounds__(256, 4)
k_main(const float* __restrict__ in_ent, const float* __restrict__ out_ent,
       const float* __restrict__ t1, const float* __restrict__ t2,
       const float* __restrict__ RR,
       const int* __restrict__ in_lab, const int* __restrict__ pos_lab,
       const int* __restrict__ neg_lab,
       const int* __restrict__ C, const uint16_t* __restrict__ rank_pos,
       const uint16_t* __restrict__ rank_neg, float* __restrict__ out) {
  int blk = blockIdx.x, t = threadIdx.x;
  int wave = t >> 6, lane = t & 63;
  int q = lane & 3, g = lane >> 2;  // 16 groups of 4 lanes

  bool is_pos = blk < 512;
  int w = (is_pos ? blk : blk - 512) * 4 + wave;
  int i = w * 16 + g;  // pair index within its class

  int il, o;
  if (is_pos) { il = in_lab[i]; o = pos_lab[i]; }
  else        { il = in_lab[i >> 3]; o = neg_lab[i]; }
  bool ei = il < ENT;
  int iid = ei ? il : il - ENT;
  bool eo = o < ENT;
  int oid = eo ? o : o - ENT;
  int key = (ei ? 0 : 2) | (eo ? 0 : 1);

  // small loads issued early (all lanes of a group load same addr -> dedup)
  int rk = is_pos ? (int)rank_pos[i] : (int)rank_neg[i];
  int cidx = is_pos ? (key * 128 + (i >> 8)) : (512 + key * 1024 + (i >> 8));
  int cbase = C[cidx];

  const float* Lp = (ei ? in_ent + (size_t)iid * D : t2 + (size_t)iid * D) + q * 4;
  const float* Rp = (eo ? out_ent + (size_t)oid * D : t1 + (size_t)oid * D) + q * 4;
  float4 L[8], R[8];
#pragma unroll
  for (int k = 0; k < 8; k++) L[k] = *(const float4*)(Lp + k * 16);
#pragma unroll
  for (int k = 0; k < 8; k++) R[k] = *(const float4*)(Rp + k * 16);

  float p = 0.f;
#pragma unroll
  for (int k = 0; k < 8; k++)
    p += L[k].x * R[k].x + L[k].y * R[k].y + L[k].z * R[k].z + L[k].w * R[k].w;
  p += __shfl_xor(p, 1, 64);
  p += __shfl_xor(p, 2, 64);

  float dot = p;
  if (!ei && !eo) dot = RR[iid * RELSZ + oid];  // rel-rel pair: exact table value

  if (is_pos) {
    if (q == 0) atomicAdd(out + cbase + rk, -logsig(dot));
    return;
  }

  // neg: dest uniform per group; tree-combine across the 8 groups of each 32-lane half
  int dest = (cbase + rk - BATCH) >> 3;
  float myval = (q == 0) ? -logsig(-dot) : 0.f;
  float v = myval;
  int d = dest;
  int eq = 1;
#pragma unroll
  for (int off = 4; off <= 16; off <<= 1) {
    float vv = __shfl_xor(v, off, 64);
    int dd = __shfl_xor(d, off, 64);
    int ee = __shfl_xor(eq, off, 64);
    eq = eq & ee & (dd == d ? 1 : 0);
    v += vv;
  }
  if (eq) {
    if (lane == 0 || lane == 32) atomicAdd(out + d, v);
  } else if (q == 0) {
    atomicAdd(out + dest, myval);
  }
}

extern "C" void kernel_launch(void* const* d_in, const int* in_sizes, int n_in,
                              void* d_out, int out_size, void* d_ws, size_t ws_size,
                              hipStream_t stream) {
  const float* in_ent  = (const float*)d_in[0];
  const float* out_ent = (const float*)d_in[1];
  const float* in_rel  = (const float*)d_in[2];
  const float* out_rel = (const float*)d_in[3];
  const float* in_map  = (const float*)d_in[4];
  const float* out_map = (const float*)d_in[5];
  const int* in_lab  = (const int*)d_in[6];
  const int* pos_lab = (const int*)d_in[7];
  const int* neg_lab = (const int*)d_in[8];

  char* ws = (char*)d_ws;
  float*    t1       = (float*)(ws + 0);
  float*    t2       = (float*)(ws + 32768);
  float*    RR       = (float*)(ws + 65536);
  int*      C        = (int*)(ws + 81920);
  uint16_t* rank_pos = (uint16_t*)(ws + 100352);
  uint16_t* rank_neg = (uint16_t*)(ws + 165888);
  float*    out      = (float*)d_out;

  k_prep<<<1184, 256, 0, stream>>>(in_rel, out_rel, in_map, out_map,
                                   in_lab, pos_lab, neg_lab,
                                   t1, t2, RR, C, rank_pos, rank_neg, out);
  k_scan<<<1, 256, 0, stream>>>(C);
  k_main<<<4608, 256, 0, stream>>>(in_ent, out_ent, t1, t2, RR,
                                   in_lab, pos_lab, neg_lab,
                                   C, rank_pos, rank_neg, out);
}